// Round 15
// baseline (193.452 us; speedup 1.0000x reference)
//
#include <hip/hip_runtime.h>
#include <stdint.h>

// Problem constants
#define EMB   1024
#define HEADS 16
#define HD    64
#define BB    2
#define TT    2048
#define MTOT  (BB*TT)

#define ELX (4194304u)         // MTOT*EMB elems
#define ELW (1048576u)         // EMB*EMB elems

#define CSCALE (0.125f * 1.44269504088896f)   // HD^-0.5 * log2(e)

typedef __attribute__((ext_vector_type(8))) short short8;
typedef __attribute__((ext_vector_type(4))) float f32x4;
typedef __attribute__((ext_vector_type(4))) unsigned short us4;

__device__ __forceinline__ float bf2f(ushort u) {
  union { uint32_t u; float f; } x; x.u = ((uint32_t)u) << 16; return x.f;
}
__device__ __forceinline__ ushort f2bf(float f) {
  union { float f; uint32_t u; } x; x.f = f;
  uint32_t u = x.u;
  u += 0x7fffu + ((u >> 16) & 1u);   // RNE
  return (ushort)(u >> 16);
}
__device__ __forceinline__ uint32_t pack2(uint32_t lo, uint32_t hi) {
  return (lo >> 16) | (hi & 0xFFFF0000u);   // [bf16(lo), bf16(hi)] truncation
}
__device__ __forceinline__ short8 pack8(f32x4 a, f32x4 b) {
  union { f32x4 v; uint32_t u[4]; } A, B;
  A.v = a; B.v = b;
  union { uint32_t d[4]; short8 s; } R;
  R.d[0] = pack2(A.u[0], A.u[1]);
  R.d[1] = pack2(A.u[2], A.u[3]);
  R.d[2] = pack2(B.u[0], B.u[1]);
  R.d[3] = pack2(B.u[2], B.u[3]);
  return R.s;
}
__device__ __forceinline__ short8 cvt8_rne(const float* f) {
  f32x4 a = *(const f32x4*)f;
  f32x4 b = *(const f32x4*)(f + 4);
  short8 r;
  r[0] = (short)f2bf(a[0]); r[1] = (short)f2bf(a[1]);
  r[2] = (short)f2bf(a[2]); r[3] = (short)f2bf(a[3]);
  r[4] = (short)f2bf(b[0]); r[5] = (short)f2bf(b[1]);
  r[6] = (short)f2bf(b[2]); r[7] = (short)f2bf(b[3]);
  return r;
}

// async global->LDS, 16B per lane; lds dest must be wave-uniform base
__device__ __forceinline__ void gll16(const void* g, void* l) {
  __builtin_amdgcn_global_load_lds((const __attribute__((address_space(1))) void*)g,
                                   (__attribute__((address_space(3))) void*)l,
                                   16, 0, 0);
}

// wave-local dtype probe over x[0..255] dwords: 1 = bf16, 0 = fp32.
__device__ __forceinline__ int probe_dtype(const uint32_t* __restrict__ x) {
  const int lane = threadIdx.x & 63;
  int cnt = 0;
#pragma unroll
  for (int i = 0; i < 4; ++i) {
    const uint32_t v = x[lane * 4 + i];
    const uint32_t e = ((v & 0xFFFFu) >> 7) & 0xFFu;
    cnt += (e >= 0x70u && e <= 0x8Fu) ? 1 : 0;
  }
#pragma unroll
  for (int off = 1; off < 64; off <<= 1) cnt += __shfl_xor(cnt, off);
  return (cnt > 128) ? 1 : 0;
}

// convert Wq,Wk,Wv -> contiguous bf16 w3[3*ELW] AND x -> xb[ELX] (RNE).
// dtype probe inlined; block 0 publishes flag. grid 3584 x 256.
__global__ __launch_bounds__(256) void convert4(const void* __restrict__ w0,
                                                const void* __restrict__ w1,
                                                const void* __restrict__ w2,
                                                const void* __restrict__ x,
                                                ushort* __restrict__ w3,
                                                ushort* __restrict__ xb,
                                                int* __restrict__ flag) {
  const int isbf = probe_dtype((const uint32_t*)x);
  if (blockIdx.x == 0 && threadIdx.x == 0) *flag = isbf;
  const size_t i = ((size_t)blockIdx.x * 256 + threadIdx.x) * 8;
  if (i < 3u * ELW) {
    const int wi = (int)(i >> 20);
    const size_t off = i & (ELW - 1);
    const void* src = (wi == 0) ? w0 : (wi == 1) ? w1 : w2;
    if (isbf) *(short8*)(w3 + i) = *(const short8*)((const ushort*)src + off);
    else      *(short8*)(w3 + i) = cvt8_rne((const float*)src + off);
  } else {
    const size_t j = i - 3u * ELW;           // 0..ELX-1
    if (isbf) *(short8*)(xb + j) = *(const short8*)((const ushort*)x + j);
    else      *(short8*)(xb + j) = cvt8_rne((const float*)x + j);
  }
}

// ---------------------------------------------------------------------------
// QKV GEMM (r13 structure, verified): m97 geometry — 128x128 tile, 4 waves,
// acc[4][4], BK=64, both operands gll16, single-buffered 32 KB LDS,
// 2 barriers/K-tile, grid 768 = 3 blocks/CU. XOR chunk swizzle.
// XCD k owns mt {4k..4k+3}; W nt-panel reused 4x within the XCD L2.
// ---------------------------------------------------------------------------
#define QSZ (128 * 64)   // elems per LDS tile (A and B each)

__device__ __forceinline__ void qkv_core(const ushort* __restrict__ xb,
                                         const ushort* __restrict__ W,
                                         int m0, int n0r,
                                         ushort* As, ushort* Bs,
                                         f32x4 acc[4][4]) {
  const int tid  = threadIdx.x;
  const int w    = tid >> 6;
  const int lane = tid & 63;
  const int quad = lane >> 4;
  const int l16  = lane & 15;
  const int wr   = w >> 1, wc = w & 1;

  const int prow = tid >> 3;                 // 0..31 (+32 per issue group)
  const int sw   = (tid & 7) ^ (prow & 7);   // pre-swizzled source chunk
  const int rsw  = l16 & 7;                  // read-side swizzle key

  for (int kt = 0; kt < 16; ++kt) {
    __syncthreads();                         // previous compute done, LDS free
#pragma unroll
    for (int g = 0; g < 4; ++g)
      gll16(xb + (size_t)(m0 + g * 32 + prow) * EMB + kt * 64 + sw * 8,
            As + g * 2048 + w * 512);
#pragma unroll
    for (int g = 0; g < 4; ++g)
      gll16(W + (size_t)(n0r + g * 32 + prow) * EMB + kt * 64 + sw * 8,
            Bs + g * 2048 + w * 512);
    __syncthreads();                         // drain glls; tile visible

#pragma unroll
    for (int ks = 0; ks < 2; ++ks) {
      const int pc = (ks * 4 + quad) ^ rsw;
      short8 a_[4], b_[4];
#pragma unroll
      for (int mi = 0; mi < 4; ++mi)
        a_[mi] = *(const short8*)&As[(wr * 64 + mi * 16 + l16) * 64 + pc * 8];
#pragma unroll
      for (int ni = 0; ni < 4; ++ni)
        b_[ni] = *(const short8*)&Bs[(wc * 64 + ni * 16 + l16) * 64 + pc * 8];
#pragma unroll
      for (int mi = 0; mi < 4; ++mi)
#pragma unroll
        for (int ni = 0; ni < 4; ++ni)
          acc[mi][ni] = __builtin_amdgcn_mfma_f32_16x16x32_bf16(a_[mi], b_[ni], acc[mi][ni], 0, 0, 0);
    }
  }
}

__global__ __launch_bounds__(256, 3) void qkv_pipe(const ushort* __restrict__ xb,
                                                   const ushort* __restrict__ w3,
                                                   const void* __restrict__ bq,
                                                   const void* __restrict__ bk,
                                                   const void* __restrict__ bv,
                                                   ushort* __restrict__ qo,
                                                   ushort* __restrict__ ko,
                                                   ushort* __restrict__ vo,
                                                   const int* __restrict__ flag) {
  __shared__ __align__(16) ushort As[QSZ];   // 16 KB
  __shared__ __align__(16) ushort Bs[QSZ];   // 16 KB
  const int bid = blockIdx.x;                // 768 blocks = 3/CU
  const int xcd = bid & 7;                   // HW round-robin: bid%8 = XCD
  const int mt  = xcd * 4 + ((bid >> 3) & 3);  // XCD k owns mt {4k..4k+3}
  const int nt  = bid >> 5;                  // 0..23
  const int m0  = mt * 128;
  const int mat = nt >> 3;
  const int n0r = (nt & 7) * 128;
  const ushort* Wp = w3 + (size_t)mat * ELW;
  const void* bias = (mat == 0) ? bq : (mat == 1) ? bk : bv;

  f32x4 acc[4][4];
#pragma unroll
  for (int a = 0; a < 4; ++a)
#pragma unroll
    for (int b = 0; b < 4; ++b) acc[a][b] = (f32x4){0.f, 0.f, 0.f, 0.f};

  qkv_core(xb, Wp, m0, n0r, As, Bs, acc);

  const int isbf = *flag;
  const int tid  = threadIdx.x;
  const int w    = tid >> 6;
  const int lane = tid & 63;
  const int quad = lane >> 4;
  const int l16  = lane & 15;
  const int wr   = w >> 1, wc = w & 1;
  ushort* dqk = (mat == 0) ? qo : ko;
  const float sc = (mat == 0) ? CSCALE : 1.0f;

#pragma unroll
  for (int ni = 0; ni < 4; ++ni) {
    const int n = n0r + wc * 64 + ni * 16 + l16;     // 0..1023 within mat
    const float bv_ = isbf ? bf2f(((const ushort*)bias)[n]) : ((const float*)bias)[n];
    const int h = n >> 6, d = n & 63;
#pragma unroll
    for (int mi = 0; mi < 4; ++mi) {
      const int m = m0 + wr * 64 + mi * 16 + quad * 4;
      const int b = m >> 11, tt = m & (TT - 1);
      if (mat == 2) {
        us4 pk;
#pragma unroll
        for (int r = 0; r < 4; ++r) pk[r] = f2bf(acc[mi][ni][r] + bv_);
        *(us4*)&vo[((size_t)((b * HEADS + h) * HD + d)) * TT + tt] = pk;
      } else {
#pragma unroll
        for (int r = 0; r < 4; ++r)
          dqk[((size_t)((b * HEADS + h) * TT + tt + r)) * HD + d] =
              f2bf((acc[mi][ni][r] + bv_) * sc);
      }
    }
  }
}

// ---------------------------------------------------------------------------
// Causal flash attention with S^T trick (QK MFMA computes S^T: A=K, B=Q).
// r15: UNIFORM PAIR BLOCKS. 1024 variable-length blocks (1..32 tiles)
// left the longest 32-tile chain running with a near-empty CU for half the
// kernel (Occupancy 22% time-avg; 4/CU resident at t=0, no refill). Now
// each block processes q-tiles p THEN 31-p sequentially: every block is
// exactly 33 tiles. 512 blocks = 2/CU, 8 waves/CU steady, no tail.
// Head-XCD locality kept (xcd = bid&7 is the head slot; 4 heads/XCD ->
// K/V L2-resident, r14-verified FETCH 62.6 -> 12.3 MB).
// Compute/staging/layout identical to r14 (pair-processing dbuf inside).
// ---------------------------------------------------------------------------
__global__ __launch_bounds__(256) void attn3(const ushort* __restrict__ qw,
                                             const ushort* __restrict__ kw,
                                             const ushort* __restrict__ vtw,
                                             ushort* __restrict__ out) {
  __shared__ __align__(16) ushort Ks[2][64 * 64];    // 16 KB
  __shared__ __align__(16) ushort Vts[2][64 * 64];   // 16 KB
  __shared__ __align__(16) ushort Ps[4][16 * 64];    // 8 KB (2 KB/wave)

  const int bid = blockIdx.x;        // 512 blocks
  const int xcd = bid & 7;           // head slot: head = hg*8 + xcd
  const int idx = bid >> 3;          // 0..63 within XCD
  const int hg  = idx >> 4;          // 0..3 head group
  const int p   = idx & 15;          // pair id: q-tiles {p, 31-p}
  const int head = hg * 8 + xcd;     // 0..31
  const int h = head & (HEADS - 1);
  const int b = head >> 4;

  const int tid  = threadIdx.x;
  const int w    = tid >> 6;
  const int lane = tid & 63;
  const int quad = lane >> 4;
  const int l16  = lane & 15;
  const int rsw  = l16 & 7;          // read-side swizzle key (fragment row&7)

  const size_t hoff = ((size_t)(b * HEADS + h)) * TT * HD;
  const ushort* Qg = qw + hoff;
  const ushort* Kg = kw + hoff;
  const ushort* Vg = vtw + hoff;     // [d][T]

  const int row = tid >> 2;          // 0..63 staging row
  const int cq  = (tid & 3) * 2;     // logical chunk pair within the row
  const int s0  = (cq)     ^ (row & 7);   // swizzled dest slots
  const int s1  = (cq + 1) ^ (row & 7);
  const int c0  = cq * 8;            // ushort col of first chunk (global src)
  const ushort* Kbase = Kg + (size_t)row * HD + c0;   // + kt*64*HD
  const ushort* Vbase = Vg + (size_t)row * TT + c0;   // + kt*64

  auto loadT = [&](int kt, short8& k0, short8& k1, short8& v0, short8& v1) {
    const size_t ko_ = (size_t)kt * 64 * HD;
    k0 = *(const short8*)(Kbase + ko_);
    k1 = *(const short8*)(Kbase + ko_ + 8);
    v0 = *(const short8*)(Vbase + kt * 64);
    v1 = *(const short8*)(Vbase + kt * 64 + 8);
  };
  auto writeT = [&](int buf, short8 k0, short8 k1, short8 v0, short8 v1) {
    *(short8*)&Ks[buf][row * 64 + s0 * 8]  = k0;
    *(short8*)&Ks[buf][row * 64 + s1 * 8]  = k1;
    *(short8*)&Vts[buf][row * 64 + s0 * 8] = v0;
    *(short8*)&Vts[buf][row * 64 + s1 * 8] = v1;
  };

  for (int qs = 0; qs < 2; ++qs) {   // uniform: 33 tiles total per block
    const int qt = qs ? (31 - p) : p;
    const int q0 = qt * 64;

    short8 qf[2];
    {
      const ushort* qrow = Qg + (size_t)(q0 + w * 16 + l16) * HD;
      qf[0] = *(const short8*)(qrow + quad * 8);
      qf[1] = *(const short8*)(qrow + 32 + quad * 8);
    }

    float lsp[4] = {0.f, 0.f, 0.f, 0.f};   // per-lane partial row sums
    f32x4 O[4];
#pragma unroll
    for (int ni = 0; ni < 4; ++ni) O[ni] = (f32x4){0.f, 0.f, 0.f, 0.f};

    auto compute_tile = [&](int kt, int buf) {
      // S^T = K . Q^T : lane(quad,l16) holds keys ni*16+quad*4+r at q-col l16
      f32x4 s[4];
#pragma unroll
      for (int ni = 0; ni < 4; ++ni) s[ni] = (f32x4){0.f, 0.f, 0.f, 0.f};
#pragma unroll
      for (int ks = 0; ks < 2; ++ks) {
#pragma unroll
        for (int ni = 0; ni < 4; ++ni) {
          short8 kb = *(const short8*)&Ks[buf][(ni * 16 + l16) * 64 +
                                              ((ks * 4 + quad) ^ rsw) * 8];
          s[ni] = __builtin_amdgcn_mfma_f32_16x16x32_bf16(kb, qf[ks], s[ni], 0, 0, 0);
        }
      }
      if (kt == qt) {   // diagonal tile: mask key > q (both local to tile)
        const int qq = w * 16 + l16;
#pragma unroll
        for (int ni = 0; ni < 4; ++ni) {
#pragma unroll
          for (int r = 0; r < 4; ++r)
            if (ni * 16 + quad * 4 + r > qq) s[ni][r] = -__builtin_inff();
        }
      }
      // p = 2^s; keys are register-contiguous -> pack pairs + b64 writes.
#pragma unroll
      for (int ni = 0; ni < 4; ++ni) {
        union { float f; uint32_t u; } p0, p1, p2, p3;
        p0.f = exp2f(s[ni][0]); p1.f = exp2f(s[ni][1]);
        p2.f = exp2f(s[ni][2]); p3.f = exp2f(s[ni][3]);
        lsp[ni] += (p0.f + p1.f) + (p2.f + p3.f);
        uint2 dw;
        dw.x = pack2(p0.u, p1.u);
        dw.y = pack2(p2.u, p3.u);
        const int slot = (2 * ni + (quad >> 1)) ^ rsw;
        *(uint2*)&Ps[w][l16 * 64 + slot * 8 + (quad & 1) * 4] = dw;
      }
      // O += P V  (A = P from wave-private LDS, B = Vt)
#pragma unroll
      for (int ks = 0; ks < 2; ++ks) {
        short8 a = *(const short8*)&Ps[w][l16 * 64 + ((ks * 4 + quad) ^ rsw) * 8];
#pragma unroll
        for (int ni = 0; ni < 4; ++ni) {
          short8 vb = *(const short8*)&Vts[buf][(ni * 16 + l16) * 64 +
                                                ((ks * 4 + quad) ^ rsw) * 8];
          O[ni] = __builtin_amdgcn_mfma_f32_16x16x32_bf16(a, vb, O[ni], 0, 0, 0);
        }
      }
    };

    // named 2-set prefetch: e = even tile of pair, o = odd tile
    short8 ek0, ek1, ev0, ev1;
    short8 ok0, ok1, ov0, ov1;
    loadT(0, ek0, ek1, ev0, ev1);
    if (qt >= 1) loadT(1, ok0, ok1, ov0, ov1);

    for (int pt = 0; ; ++pt) {
      const int t0 = 2 * pt, t1 = t0 + 1;
      __syncthreads();                       // previous pair's compute done
      writeT(0, ek0, ek1, ev0, ev1);
      if (t1 <= qt) writeT(1, ok0, ok1, ov0, ov1);
      if (t0 + 2 <= qt) loadT(t0 + 2, ek0, ek1, ev0, ev1);
      if (t1 + 2 <= qt) loadT(t1 + 2, ok0, ok1, ov0, ov1);
      __syncthreads();                       // staged pair visible
      compute_tile(t0, 0);
      if (t1 <= qt) compute_tile(t1, 1);
      if (t1 >= qt) break;
    }

    // reduce ls across quads (each lane then holds total for q = l16)
    float lst = (lsp[0] + lsp[1]) + (lsp[2] + lsp[3]);
    lst += __shfl_xor(lst, 16);
    lst += __shfl_xor(lst, 32);

#pragma unroll
    for (int r = 0; r < 4; ++r) {
      const float inv = 1.0f / __shfl(lst, (lane & 48) | (quad * 4 + r));
      const int t = q0 + w * 16 + quad * 4 + r;
#pragma unroll
      for (int ni = 0; ni < 4; ++ni) {
        out[((size_t)(b * TT + t)) * EMB + h * HD + ni * 16 + l16] = f2bf(O[ni][r] * inv);
      }
    }
  }
}

// ---------------------------------------------------------------------------
// Output projection (r12 structure, unchanged): x2 literal-offset unroll.
// Tile 128m x 128n, BK=64, 512 threads / 8 waves (2x4), acc[4][2].
// A (o_ws, always bf16) via gll16. B (Wo): bf16 -> gll16; fp32 -> reg-stage
// + pack8 + write-late swizzled ds_write. Grid 256 = 1 block/CU.
// ---------------------------------------------------------------------------
#define PASZ (128 * 64)

template<bool WBF>
__device__ __forceinline__ void proj_core(const ushort* __restrict__ A,
                                          const void* __restrict__ Wo,
                                          int m0, int n0,
                                          ushort* As2, ushort* Bs2,
                                          f32x4 acc[4][2]) {
  const int tid  = threadIdx.x;
  const int w    = tid >> 6;
  const int lane = tid & 63;
  const int quad = lane >> 4;
  const int l16  = lane & 15;
  const int wr   = w >> 2, wc = w & 3;

  const int prow = tid >> 3;               // 0..63 (issue-group row)
  const int sw   = (tid & 7) ^ (prow & 7); // pre-swizzled source chunk
  const int rsw  = l16 & 7;                // read-side swizzle key

  const ushort* Wu = (const ushort*)Wo;
  const float*  Wf = (const float*)Wo;
  f32x4 wreg[4];

  auto stageA = [&](ushort* dst, int kt) {
#pragma unroll
    for (int g = 0; g < 2; ++g)
      gll16(A + (size_t)(m0 + g * 64 + prow) * EMB + kt * 64 + sw * 8,
            dst + g * 4096 + w * 512);
  };
  auto stageB_gll = [&](ushort* dst, int kt) {
#pragma unroll
    for (int g = 0; g < 2; ++g)
      gll16(Wu + (size_t)(n0 + g * 64 + prow) * EMB + kt * 64 + sw * 8,
            dst + g * 4096 + w * 512);
  };
  auto stageB_issue = [&](int kt) {
#pragma unroll
    for (int g = 0; g < 2; ++g) {
      const float* src = Wf + (size_t)(n0 + g * 64 + prow) * EMB + kt * 64 + sw * 8;
      wreg[2 * g]     = *(const f32x4*)(src);
      wreg[2 * g + 1] = *(const f32x4*)(src + 4);
    }
  };
  auto stageB_write = [&](ushort* dst) {   // physical chunk g*512+tid (linear)
#pragma unroll
    for (int g = 0; g < 2; ++g)
      *(short8*)&dst[((size_t)g * 512 + tid) * 8] = pack8(wreg[2 * g], wreg[2 * g + 1]);
  };
  auto compute = [&](const ushort* Ab, const ushort* Bb) {
    short8 bf_[2][2];
#pragma unroll
    for (int ni = 0; ni < 2; ++ni)
#pragma unroll
      for (int ks = 0; ks < 2; ++ks)
        bf_[ni][ks] = *(const short8*)&Bb[(wc * 32 + ni * 16 + l16) * 64 +
                                          ((ks * 4 + quad) ^ rsw) * 8];
#pragma unroll
    for (int mi = 0; mi < 4; ++mi) {
      const int arow = (wr * 64 + mi * 16 + l16) * 64;
      short8 a0 = *(const short8*)&Ab[arow + ((quad) ^ rsw) * 8];
      short8 a1 = *(const short8*)&Ab[arow + ((4 + quad) ^ rsw) * 8];
#pragma unroll
      for (int ni = 0; ni < 2; ++ni) {
        acc[mi][ni] = __builtin_amdgcn_mfma_f32_16x16x32_bf16(a0, bf_[ni][0], acc[mi][ni], 0, 0, 0);
        acc[mi][ni] = __builtin_amdgcn_mfma_f32_16x16x32_bf16(a1, bf_[ni][1], acc[mi][ni], 0, 0, 0);
      }
    }
  };

  stageA(As2, 0);
  if constexpr (WBF) stageB_gll(Bs2, 0);
  else { stageB_issue(0); stageB_write(Bs2); }
  __syncthreads();

  for (int tp = 0; tp < 8; ++tp) {
    const int t0 = 2 * tp;
    // iter A: compute buf0 (tile t0), stage tile t0+1 into buf1
    stageA(As2 + PASZ, t0 + 1);
    if constexpr (WBF) stageB_gll(Bs2 + PASZ, t0 + 1);
    else stageB_issue(t0 + 1);
    compute(As2, Bs2);
    if constexpr (!WBF) stageB_write(Bs2 + PASZ);   // write-late
    __syncthreads();
    // iter B: compute buf1 (tile t0+1), stage tile t0+2 into buf0
    if (tp < 7) {
      stageA(As2, t0 + 2);
      if constexpr (WBF) stageB_gll(Bs2, t0 + 2);
      else stageB_issue(t0 + 2);
    }
    compute(As2 + PASZ, Bs2 + PASZ);
    if constexpr (!WBF) { if (tp < 7) stageB_write(Bs2); }
    __syncthreads();
  }
}

__global__ __launch_bounds__(512, 2) void proj_pipe(const ushort* __restrict__ A,
                                                    const void* __restrict__ Wo,
                                                    const void* __restrict__ bo,
                                                    void* __restrict__ out,
                                                    const int* __restrict__ flag) {
  __shared__ __align__(16) ushort As2[2 * PASZ];   // 32 KB
  __shared__ __align__(16) ushort Bs2[2 * PASZ];   // 32 KB
  const int bid = blockIdx.x;              // 256 blocks, 1/CU
  const int xcd = bid & 7;
  const int mt  = xcd * 4 + ((bid >> 3) & 3);  // XCD k owns mt {4k..4k+3}
  const int nt  = bid >> 5;                // 0..7
  const int m0  = mt * 128;
  const int n0  = nt * 128;

  f32x4 acc[4][2];
#pragma unroll
  for (int i = 0; i < 4; ++i)
#pragma unroll
    for (int jj = 0; jj < 2; ++jj) acc[i][jj] = (f32x4){0.f, 0.f, 0.f, 0.f};

  const int isbf = *flag;
  if (isbf) proj_core<true >(A, Wo, m0, n0, As2, Bs2, acc);
  else      proj_core<false>(A, Wo, m0, n0, As2, Bs2, acc);

  const int tid  = threadIdx.x;
  const int w    = tid >> 6;
  const int lane = tid & 63;
  const int quad = lane >> 4;
  const int l16  = lane & 15;
  const int wr   = w >> 2, wc = w & 3;

#pragma unroll
  for (int ni = 0; ni < 2; ++ni) {
    const int n = n0 + wc * 32 + ni * 16 + l16;
    const float bv_ = isbf ? bf2f(((const ushort*)bo)[n]) : ((const float*)bo)[n];
#pragma unroll
    for (int mi = 0; mi < 4; ++mi) {
#pragma unroll
      for (int r = 0; r < 4; ++r) {
        const int m = m0 + wr * 64 + mi * 16 + quad * 4 + r;
        const float v = acc[mi][ni][r] + bv_;
        if (isbf) ((ushort*)out)[(size_t)m * EMB + n] = f2bf(v);
        else      ((float*) out)[(size_t)m * EMB + n] = v;
      }
    }
  }
}

// ---------------------------------------------------------------------------
extern "C" void kernel_launch(void* const* d_in, const int* in_sizes, int n_in,
                              void* d_out, int out_size, void* d_ws, size_t ws_size,
                              hipStream_t stream) {
  const void* x  = d_in[0];
  const void* Wq = d_in[1];
  const void* bq = d_in[2];
  const void* Wk = d_in[3];
  const void* bk = d_in[4];
  const void* Wv = d_in[5];
  const void* bv = d_in[6];
  const void* Wo = d_in[7];
  const void* bo = d_in[8];

  int* flag = (int*)d_ws;
  ushort* base = (ushort*)((char*)d_ws + 256);

  // ws layout (33.56 MB budget):
  //   q:[0,ELX) k:[ELX,2ELX) vt:[2ELX,3ELX)
  //   w3 (3*ELW, dead after qkv) and o (ELX) share [3ELX,4ELX)
  // xb (bf16 copy of x, ELX ushorts) lives in d_out: dead before proj_pipe
  // writes it.
  ushort* q_ws  = base;
  ushort* k_ws  = q_ws + ELX;
  ushort* vt_ws = k_ws + ELX;
  ushort* w3    = vt_ws + ELX;
  ushort* o_ws  = vt_ws + ELX;
  ushort* xb    = (ushort*)d_out;

  convert4<<<dim3(3584), dim3(256), 0, stream>>>(Wq, Wk, Wv, x, w3, xb, flag);
  qkv_pipe<<<dim3(768), dim3(256), 0, stream>>>(xb, w3, bq, bk, bv,
                                                q_ws, k_ws, vt_ws, flag);
  attn3<<<dim3(512), dim3(256), 0, stream>>>(q_ws, k_ws, vt_ws, o_ws);
  proj_pipe<<<dim3(256), dim3(512), 0, stream>>>(o_ws, Wo, bo, d_out, flag);
}

// Round 16
// 189.088 us; speedup vs baseline: 1.0231x; 1.0231x over previous
//
#include <hip/hip_runtime.h>
#include <stdint.h>

// Problem constants
#define EMB   1024
#define HEADS 16
#define HD    64
#define BB    2
#define TT    2048
#define MTOT  (BB*TT)

#define ELX (4194304u)         // MTOT*EMB elems
#define ELW (1048576u)         // EMB*EMB elems

#define CSCALE (0.125f * 1.44269504088896f)   // HD^-0.5 * log2(e)

typedef __attribute__((ext_vector_type(8))) short short8;
typedef __attribute__((ext_vector_type(4))) float f32x4;
typedef __attribute__((ext_vector_type(4))) unsigned short us4;

__device__ __forceinline__ float bf2f(ushort u) {
  union { uint32_t u; float f; } x; x.u = ((uint32_t)u) << 16; return x.f;
}
__device__ __forceinline__ ushort f2bf(float f) {
  union { float f; uint32_t u; } x; x.f = f;
  uint32_t u = x.u;
  u += 0x7fffu + ((u >> 16) & 1u);   // RNE
  return (ushort)(u >> 16);
}
__device__ __forceinline__ uint32_t pack2(uint32_t lo, uint32_t hi) {
  return (lo >> 16) | (hi & 0xFFFF0000u);   // [bf16(lo), bf16(hi)] truncation
}
__device__ __forceinline__ short8 pack8(f32x4 a, f32x4 b) {
  union { f32x4 v; uint32_t u[4]; } A, B;
  A.v = a; B.v = b;
  union { uint32_t d[4]; short8 s; } R;
  R.d[0] = pack2(A.u[0], A.u[1]);
  R.d[1] = pack2(A.u[2], A.u[3]);
  R.d[2] = pack2(B.u[0], B.u[1]);
  R.d[3] = pack2(B.u[2], B.u[3]);
  return R.s;
}
__device__ __forceinline__ short8 cvt8_rne(const float* f) {
  f32x4 a = *(const f32x4*)f;
  f32x4 b = *(const f32x4*)(f + 4);
  short8 r;
  r[0] = (short)f2bf(a[0]); r[1] = (short)f2bf(a[1]);
  r[2] = (short)f2bf(a[2]); r[3] = (short)f2bf(a[3]);
  r[4] = (short)f2bf(b[0]); r[5] = (short)f2bf(b[1]);
  r[6] = (short)f2bf(b[2]); r[7] = (short)f2bf(b[3]);
  return r;
}

// async global->LDS, 16B per lane; lds dest must be wave-uniform base
__device__ __forceinline__ void gll16(const void* g, void* l) {
  __builtin_amdgcn_global_load_lds((const __attribute__((address_space(1))) void*)g,
                                   (__attribute__((address_space(3))) void*)l,
                                   16, 0, 0);
}

// wave-local dtype probe over x[0..255] dwords: 1 = bf16, 0 = fp32.
__device__ __forceinline__ int probe_dtype(const uint32_t* __restrict__ x) {
  const int lane = threadIdx.x & 63;
  int cnt = 0;
#pragma unroll
  for (int i = 0; i < 4; ++i) {
    const uint32_t v = x[lane * 4 + i];
    const uint32_t e = ((v & 0xFFFFu) >> 7) & 0xFFu;
    cnt += (e >= 0x70u && e <= 0x8Fu) ? 1 : 0;
  }
#pragma unroll
  for (int off = 1; off < 64; off <<= 1) cnt += __shfl_xor(cnt, off);
  return (cnt > 128) ? 1 : 0;
}

// convert Wq,Wk,Wv -> contiguous bf16 w3[3*ELW] AND x -> xb[ELX] (RNE).
// dtype probe inlined; block 0 publishes flag. grid 3584 x 256.
__global__ __launch_bounds__(256) void convert4(const void* __restrict__ w0,
                                                const void* __restrict__ w1,
                                                const void* __restrict__ w2,
                                                const void* __restrict__ x,
                                                ushort* __restrict__ w3,
                                                ushort* __restrict__ xb,
                                                int* __restrict__ flag) {
  const int isbf = probe_dtype((const uint32_t*)x);
  if (blockIdx.x == 0 && threadIdx.x == 0) *flag = isbf;
  const size_t i = ((size_t)blockIdx.x * 256 + threadIdx.x) * 8;
  if (i < 3u * ELW) {
    const int wi = (int)(i >> 20);
    const size_t off = i & (ELW - 1);
    const void* src = (wi == 0) ? w0 : (wi == 1) ? w1 : w2;
    if (isbf) *(short8*)(w3 + i) = *(const short8*)((const ushort*)src + off);
    else      *(short8*)(w3 + i) = cvt8_rne((const float*)src + off);
  } else {
    const size_t j = i - 3u * ELW;           // 0..ELX-1
    if (isbf) *(short8*)(xb + j) = *(const short8*)((const ushort*)x + j);
    else      *(short8*)(xb + j) = cvt8_rne((const float*)x + j);
  }
}

// ---------------------------------------------------------------------------
// QKV GEMM (r13 structure, verified): m97 geometry — 128x128 tile, 4 waves,
// acc[4][4], BK=64, both operands gll16, single-buffered 32 KB LDS,
// 2 barriers/K-tile, grid 768 = 3 blocks/CU. XOR chunk swizzle.
// XCD k owns mt {4k..4k+3}; W nt-panel reused 4x within the XCD L2.
// ---------------------------------------------------------------------------
#define QSZ (128 * 64)   // elems per LDS tile (A and B each)

__device__ __forceinline__ void qkv_core(const ushort* __restrict__ xb,
                                         const ushort* __restrict__ W,
                                         int m0, int n0r,
                                         ushort* As, ushort* Bs,
                                         f32x4 acc[4][4]) {
  const int tid  = threadIdx.x;
  const int w    = tid >> 6;
  const int lane = tid & 63;
  const int quad = lane >> 4;
  const int l16  = lane & 15;
  const int wr   = w >> 1, wc = w & 1;

  const int prow = tid >> 3;                 // 0..31 (+32 per issue group)
  const int sw   = (tid & 7) ^ (prow & 7);   // pre-swizzled source chunk
  const int rsw  = l16 & 7;                  // read-side swizzle key

  for (int kt = 0; kt < 16; ++kt) {
    __syncthreads();                         // previous compute done, LDS free
#pragma unroll
    for (int g = 0; g < 4; ++g)
      gll16(xb + (size_t)(m0 + g * 32 + prow) * EMB + kt * 64 + sw * 8,
            As + g * 2048 + w * 512);
#pragma unroll
    for (int g = 0; g < 4; ++g)
      gll16(W + (size_t)(n0r + g * 32 + prow) * EMB + kt * 64 + sw * 8,
            Bs + g * 2048 + w * 512);
    __syncthreads();                         // drain glls; tile visible

#pragma unroll
    for (int ks = 0; ks < 2; ++ks) {
      const int pc = (ks * 4 + quad) ^ rsw;
      short8 a_[4], b_[4];
#pragma unroll
      for (int mi = 0; mi < 4; ++mi)
        a_[mi] = *(const short8*)&As[(wr * 64 + mi * 16 + l16) * 64 + pc * 8];
#pragma unroll
      for (int ni = 0; ni < 4; ++ni)
        b_[ni] = *(const short8*)&Bs[(wc * 64 + ni * 16 + l16) * 64 + pc * 8];
#pragma unroll
      for (int mi = 0; mi < 4; ++mi)
#pragma unroll
        for (int ni = 0; ni < 4; ++ni)
          acc[mi][ni] = __builtin_amdgcn_mfma_f32_16x16x32_bf16(a_[mi], b_[ni], acc[mi][ni], 0, 0, 0);
    }
  }
}

__global__ __launch_bounds__(256, 3) void qkv_pipe(const ushort* __restrict__ xb,
                                                   const ushort* __restrict__ w3,
                                                   const void* __restrict__ bq,
                                                   const void* __restrict__ bk,
                                                   const void* __restrict__ bv,
                                                   ushort* __restrict__ qo,
                                                   ushort* __restrict__ ko,
                                                   ushort* __restrict__ vo,
                                                   const int* __restrict__ flag) {
  __shared__ __align__(16) ushort As[QSZ];   // 16 KB
  __shared__ __align__(16) ushort Bs[QSZ];   // 16 KB
  const int bid = blockIdx.x;                // 768 blocks = 3/CU
  const int xcd = bid & 7;                   // HW round-robin: bid%8 = XCD
  const int mt  = xcd * 4 + ((bid >> 3) & 3);  // XCD k owns mt {4k..4k+3}
  const int nt  = bid >> 5;                  // 0..23
  const int m0  = mt * 128;
  const int mat = nt >> 3;
  const int n0r = (nt & 7) * 128;
  const ushort* Wp = w3 + (size_t)mat * ELW;
  const void* bias = (mat == 0) ? bq : (mat == 1) ? bk : bv;

  f32x4 acc[4][4];
#pragma unroll
  for (int a = 0; a < 4; ++a)
#pragma unroll
    for (int b = 0; b < 4; ++b) acc[a][b] = (f32x4){0.f, 0.f, 0.f, 0.f};

  qkv_core(xb, Wp, m0, n0r, As, Bs, acc);

  const int isbf = *flag;
  const int tid  = threadIdx.x;
  const int w    = tid >> 6;
  const int lane = tid & 63;
  const int quad = lane >> 4;
  const int l16  = lane & 15;
  const int wr   = w >> 1, wc = w & 1;
  ushort* dqk = (mat == 0) ? qo : ko;
  const float sc = (mat == 0) ? CSCALE : 1.0f;

#pragma unroll
  for (int ni = 0; ni < 4; ++ni) {
    const int n = n0r + wc * 64 + ni * 16 + l16;     // 0..1023 within mat
    const float bv_ = isbf ? bf2f(((const ushort*)bias)[n]) : ((const float*)bias)[n];
    const int h = n >> 6, d = n & 63;
#pragma unroll
    for (int mi = 0; mi < 4; ++mi) {
      const int m = m0 + wr * 64 + mi * 16 + quad * 4;
      const int b = m >> 11, tt = m & (TT - 1);
      if (mat == 2) {
        us4 pk;
#pragma unroll
        for (int r = 0; r < 4; ++r) pk[r] = f2bf(acc[mi][ni][r] + bv_);
        *(us4*)&vo[((size_t)((b * HEADS + h) * HD + d)) * TT + tt] = pk;
      } else {
#pragma unroll
        for (int r = 0; r < 4; ++r)
          dqk[((size_t)((b * HEADS + h) * TT + tt + r)) * HD + d] =
              f2bf((acc[mi][ni][r] + bv_) * sc);
      }
    }
  }
}

// ---------------------------------------------------------------------------
// Causal flash attention with S^T trick (QK MFMA computes S^T: A=K, B=Q).
// r16: EXACT r14 structure (49.7 µs verified; r15's uniform-pair merge
// regressed via VGPR 64->84 and halved resident blocks — reverted).
// Head-XCD-local map (FETCH 62.6 -> 12.3 MB verified). Added T5:
// s_setprio(1) around the MFMA clusters — m191 measured +4-7% for attn
// with multiple independent blocks per CU at different phases (ours: 4/CU).
// ---------------------------------------------------------------------------
__global__ __launch_bounds__(256) void attn3(const ushort* __restrict__ qw,
                                             const ushort* __restrict__ kw,
                                             const ushort* __restrict__ vtw,
                                             ushort* __restrict__ out) {
  __shared__ __align__(16) ushort Ks[2][64 * 64];    // 16 KB
  __shared__ __align__(16) ushort Vts[2][64 * 64];   // 16 KB
  __shared__ __align__(16) ushort Ps[4][16 * 64];    // 8 KB (2 KB/wave)

  const int bid = blockIdx.x;
  const int xcd = bid & 7;           // head slot: head = hg*8 + xcd
  const int idx = bid >> 3;          // 0..127 within XCD
  const int hg  = idx >> 5;          // 0..3 head group
  const int qh  = idx & 31;
  int qt;                            // balanced qt swizzle per head-group
  if      (hg == 0) qt = qh;
  else if (hg == 1) qt = 31 - qh;
  else if (hg == 2) qt = (qh + 16) & 31;
  else              qt = 31 - ((qh + 16) & 31);
  const int head = hg * 8 + xcd;     // 0..31
  const int h = head & (HEADS - 1);
  const int b = head >> 4;

  const int tid  = threadIdx.x;
  const int w    = tid >> 6;
  const int lane = tid & 63;
  const int quad = lane >> 4;
  const int l16  = lane & 15;
  const int rsw  = l16 & 7;          // read-side swizzle key (fragment row&7)

  const size_t hoff = ((size_t)(b * HEADS + h)) * TT * HD;
  const ushort* Qg = qw + hoff;
  const ushort* Kg = kw + hoff;
  const ushort* Vg = vtw + hoff;     // [d][T]
  const int q0 = qt * 64;

  short8 qf[2];
  {
    const ushort* qrow = Qg + (size_t)(q0 + w * 16 + l16) * HD;
    qf[0] = *(const short8*)(qrow + quad * 8);
    qf[1] = *(const short8*)(qrow + 32 + quad * 8);
  }

  const int row = tid >> 2;          // 0..63 staging row
  const int cq  = (tid & 3) * 2;     // logical chunk pair within the row
  const int s0  = (cq)     ^ (row & 7);   // swizzled dest slots
  const int s1  = (cq + 1) ^ (row & 7);
  const int c0  = cq * 8;            // ushort col of first chunk (global src)
  const ushort* Kbase = Kg + (size_t)row * HD + c0;   // + kt*64*HD
  const ushort* Vbase = Vg + (size_t)row * TT + c0;   // + kt*64

  float lsp[4] = {0.f, 0.f, 0.f, 0.f};   // per-lane partial row sums, q = l16
  f32x4 O[4];
#pragma unroll
  for (int ni = 0; ni < 4; ++ni) O[ni] = (f32x4){0.f, 0.f, 0.f, 0.f};

  auto loadT = [&](int kt, short8& k0, short8& k1, short8& v0, short8& v1) {
    const size_t ko_ = (size_t)kt * 64 * HD;
    k0 = *(const short8*)(Kbase + ko_);
    k1 = *(const short8*)(Kbase + ko_ + 8);
    v0 = *(const short8*)(Vbase + kt * 64);
    v1 = *(const short8*)(Vbase + kt * 64 + 8);
  };
  auto writeT = [&](int buf, short8 k0, short8 k1, short8 v0, short8 v1) {
    *(short8*)&Ks[buf][row * 64 + s0 * 8]  = k0;
    *(short8*)&Ks[buf][row * 64 + s1 * 8]  = k1;
    *(short8*)&Vts[buf][row * 64 + s0 * 8] = v0;
    *(short8*)&Vts[buf][row * 64 + s1 * 8] = v1;
  };

  auto compute_tile = [&](int kt, int buf) {
    // S^T = K . Q^T : lane(quad,l16) holds keys ni*16+quad*4+r at q-col l16
    f32x4 s[4];
#pragma unroll
    for (int ni = 0; ni < 4; ++ni) s[ni] = (f32x4){0.f, 0.f, 0.f, 0.f};
    __builtin_amdgcn_s_setprio(1);
#pragma unroll
    for (int ks = 0; ks < 2; ++ks) {
#pragma unroll
      for (int ni = 0; ni < 4; ++ni) {
        short8 kb = *(const short8*)&Ks[buf][(ni * 16 + l16) * 64 +
                                            ((ks * 4 + quad) ^ rsw) * 8];
        s[ni] = __builtin_amdgcn_mfma_f32_16x16x32_bf16(kb, qf[ks], s[ni], 0, 0, 0);
      }
    }
    __builtin_amdgcn_s_setprio(0);
    if (kt == qt) {   // diagonal tile: mask key > q (both local to the tile)
      const int qq = w * 16 + l16;
#pragma unroll
      for (int ni = 0; ni < 4; ++ni) {
#pragma unroll
        for (int r = 0; r < 4; ++r)
          if (ni * 16 + quad * 4 + r > qq) s[ni][r] = -__builtin_inff();
      }
    }
    // p = 2^s; keys are register-contiguous -> pack pairs + b64 writes.
#pragma unroll
    for (int ni = 0; ni < 4; ++ni) {
      union { float f; uint32_t u; } p0, p1, p2, p3;
      p0.f = exp2f(s[ni][0]); p1.f = exp2f(s[ni][1]);
      p2.f = exp2f(s[ni][2]); p3.f = exp2f(s[ni][3]);
      lsp[ni] += (p0.f + p1.f) + (p2.f + p3.f);
      uint2 dw;
      dw.x = pack2(p0.u, p1.u);
      dw.y = pack2(p2.u, p3.u);
      const int slot = (2 * ni + (quad >> 1)) ^ rsw;
      *(uint2*)&Ps[w][l16 * 64 + slot * 8 + (quad & 1) * 4] = dw;
    }
    // O += P V  (A = P from wave-private LDS, B = Vt)
    __builtin_amdgcn_s_setprio(1);
#pragma unroll
    for (int ks = 0; ks < 2; ++ks) {
      short8 a = *(const short8*)&Ps[w][l16 * 64 + ((ks * 4 + quad) ^ rsw) * 8];
#pragma unroll
      for (int ni = 0; ni < 4; ++ni) {
        short8 vb = *(const short8*)&Vts[buf][(ni * 16 + l16) * 64 +
                                              ((ks * 4 + quad) ^ rsw) * 8];
        O[ni] = __builtin_amdgcn_mfma_f32_16x16x32_bf16(a, vb, O[ni], 0, 0, 0);
      }
    }
    __builtin_amdgcn_s_setprio(0);
  };

  // named 2-set prefetch: e = even tile of pair, o = odd tile
  short8 ek0, ek1, ev0, ev1;
  short8 ok0, ok1, ov0, ov1;
  loadT(0, ek0, ek1, ev0, ev1);
  if (qt >= 1) loadT(1, ok0, ok1, ov0, ov1);

  for (int pt = 0; ; ++pt) {
    const int t0 = 2 * pt, t1 = t0 + 1;
    __syncthreads();                       // previous pair's compute done
    writeT(0, ek0, ek1, ev0, ev1);
    if (t1 <= qt) writeT(1, ok0, ok1, ov0, ov1);
    if (t0 + 2 <= qt) loadT(t0 + 2, ek0, ek1, ev0, ev1);
    if (t1 + 2 <= qt) loadT(t1 + 2, ok0, ok1, ov0, ov1);
    __syncthreads();                       // staged pair visible
    compute_tile(t0, 0);
    if (t1 <= qt) compute_tile(t1, 1);
    if (t1 >= qt) break;
  }

  // reduce ls across quads (each lane then holds total for q = l16)
  float lst = (lsp[0] + lsp[1]) + (lsp[2] + lsp[3]);
  lst += __shfl_xor(lst, 16);
  lst += __shfl_xor(lst, 32);

#pragma unroll
  for (int r = 0; r < 4; ++r) {
    const float inv = 1.0f / __shfl(lst, (lane & 48) | (quad * 4 + r));
    const int t = q0 + w * 16 + quad * 4 + r;
#pragma unroll
    for (int ni = 0; ni < 4; ++ni) {
      out[((size_t)(b * TT + t)) * EMB + h * HD + ni * 16 + l16] = f2bf(O[ni][r] * inv);
    }
  }
}

// ---------------------------------------------------------------------------
// Output projection (r12 structure, unchanged): x2 literal-offset unroll.
// Tile 128m x 128n, BK=64, 512 threads / 8 waves (2x4), acc[4][2].
// A (o_ws, always bf16) via gll16. B (Wo): bf16 -> gll16; fp32 -> reg-stage
// + pack8 + write-late swizzled ds_write. Grid 256 = 1 block/CU.
// ---------------------------------------------------------------------------
#define PASZ (128 * 64)

template<bool WBF>
__device__ __forceinline__ void proj_core(const ushort* __restrict__ A,
                                          const void* __restrict__ Wo,
                                          int m0, int n0,
                                          ushort* As2, ushort* Bs2,
                                          f32x4 acc[4][2]) {
  const int tid  = threadIdx.x;
  const int w    = tid >> 6;
  const int lane = tid & 63;
  const int quad = lane >> 4;
  const int l16  = lane & 15;
  const int wr   = w >> 2, wc = w & 3;

  const int prow = tid >> 3;               // 0..63 (issue-group row)
  const int sw   = (tid & 7) ^ (prow & 7); // pre-swizzled source chunk
  const int rsw  = l16 & 7;                // read-side swizzle key

  const ushort* Wu = (const ushort*)Wo;
  const float*  Wf = (const float*)Wo;
  f32x4 wreg[4];

  auto stageA = [&](ushort* dst, int kt) {
#pragma unroll
    for (int g = 0; g < 2; ++g)
      gll16(A + (size_t)(m0 + g * 64 + prow) * EMB + kt * 64 + sw * 8,
            dst + g * 4096 + w * 512);
  };
  auto stageB_gll = [&](ushort* dst, int kt) {
#pragma unroll
    for (int g = 0; g < 2; ++g)
      gll16(Wu + (size_t)(n0 + g * 64 + prow) * EMB + kt * 64 + sw * 8,
            dst + g * 4096 + w * 512);
  };
  auto stageB_issue = [&](int kt) {
#pragma unroll
    for (int g = 0; g < 2; ++g) {
      const float* src = Wf + (size_t)(n0 + g * 64 + prow) * EMB + kt * 64 + sw * 8;
      wreg[2 * g]     = *(const f32x4*)(src);
      wreg[2 * g + 1] = *(const f32x4*)(src + 4);
    }
  };
  auto stageB_write = [&](ushort* dst) {   // physical chunk g*512+tid (linear)
#pragma unroll
    for (int g = 0; g < 2; ++g)
      *(short8*)&dst[((size_t)g * 512 + tid) * 8] = pack8(wreg[2 * g], wreg[2 * g + 1]);
  };
  auto compute = [&](const ushort* Ab, const ushort* Bb) {
    short8 bf_[2][2];
#pragma unroll
    for (int ni = 0; ni < 2; ++ni)
#pragma unroll
      for (int ks = 0; ks < 2; ++ks)
        bf_[ni][ks] = *(const short8*)&Bb[(wc * 32 + ni * 16 + l16) * 64 +
                                          ((ks * 4 + quad) ^ rsw) * 8];
#pragma unroll
    for (int mi = 0; mi < 4; ++mi) {
      const int arow = (wr * 64 + mi * 16 + l16) * 64;
      short8 a0 = *(const short8*)&Ab[arow + ((quad) ^ rsw) * 8];
      short8 a1 = *(const short8*)&Ab[arow + ((4 + quad) ^ rsw) * 8];
#pragma unroll
      for (int ni = 0; ni < 2; ++ni) {
        acc[mi][ni] = __builtin_amdgcn_mfma_f32_16x16x32_bf16(a0, bf_[ni][0], acc[mi][ni], 0, 0, 0);
        acc[mi][ni] = __builtin_amdgcn_mfma_f32_16x16x32_bf16(a1, bf_[ni][1], acc[mi][ni], 0, 0, 0);
      }
    }
  };

  stageA(As2, 0);
  if constexpr (WBF) stageB_gll(Bs2, 0);
  else { stageB_issue(0); stageB_write(Bs2); }
  __syncthreads();

  for (int tp = 0; tp < 8; ++tp) {
    const int t0 = 2 * tp;
    // iter A: compute buf0 (tile t0), stage tile t0+1 into buf1
    stageA(As2 + PASZ, t0 + 1);
    if constexpr (WBF) stageB_gll(Bs2 + PASZ, t0 + 1);
    else stageB_issue(t0 + 1);
    compute(As2, Bs2);
    if constexpr (!WBF) stageB_write(Bs2 + PASZ);   // write-late
    __syncthreads();
    // iter B: compute buf1 (tile t0+1), stage tile t0+2 into buf0
    if (tp < 7) {
      stageA(As2, t0 + 2);
      if constexpr (WBF) stageB_gll(Bs2, t0 + 2);
      else stageB_issue(t0 + 2);
    }
    compute(As2 + PASZ, Bs2 + PASZ);
    if constexpr (!WBF) { if (tp < 7) stageB_write(Bs2); }
    __syncthreads();
  }
}

__global__ __launch_bounds__(512, 2) void proj_pipe(const ushort* __restrict__ A,
                                                    const void* __restrict__ Wo,
                                                    const void* __restrict__ bo,
                                                    void* __restrict__ out,
                                                    const int* __restrict__ flag) {
  __shared__ __align__(16) ushort As2[2 * PASZ];   // 32 KB
  __shared__ __align__(16) ushort Bs2[2 * PASZ];   // 32 KB
  const int bid = blockIdx.x;              // 256 blocks, 1/CU
  const int xcd = bid & 7;
  const int mt  = xcd * 4 + ((bid >> 3) & 3);  // XCD k owns mt {4k..4k+3}
  const int nt  = bid >> 5;                // 0..7
  const int m0  = mt * 128;
  const int n0  = nt * 128;

  f32x4 acc[4][2];
#pragma unroll
  for (int i = 0; i < 4; ++i)
#pragma unroll
    for (int jj = 0; jj < 2; ++jj) acc[i][jj] = (f32x4){0.f, 0.f, 0.f, 0.f};

  const int isbf = *flag;
  if (isbf) proj_core<true >(A, Wo, m0, n0, As2, Bs2, acc);
  else      proj_core<false>(A, Wo, m0, n0, As2, Bs2, acc);

  const int tid  = threadIdx.x;
  const int w    = tid >> 6;
  const int lane = tid & 63;
  const int quad = lane >> 4;
  const int l16  = lane & 15;
  const int wr   = w >> 2, wc = w & 3;

#pragma unroll
  for (int ni = 0; ni < 2; ++ni) {
    const int n = n0 + wc * 32 + ni * 16 + l16;
    const float bv_ = isbf ? bf2f(((const ushort*)bo)[n]) : ((const float*)bo)[n];
#pragma unroll
    for (int mi = 0; mi < 4; ++mi) {
#pragma unroll
      for (int r = 0; r < 4; ++r) {
        const int m = m0 + wr * 64 + mi * 16 + quad * 4 + r;
        const float v = acc[mi][ni][r] + bv_;
        if (isbf) ((ushort*)out)[(size_t)m * EMB + n] = f2bf(v);
        else      ((float*) out)[(size_t)m * EMB + n] = v;
      }
    }
  }
}

// ---------------------------------------------------------------------------
extern "C" void kernel_launch(void* const* d_in, const int* in_sizes, int n_in,
                              void* d_out, int out_size, void* d_ws, size_t ws_size,
                              hipStream_t stream) {
  const void* x  = d_in[0];
  const void* Wq = d_in[1];
  const void* bq = d_in[2];
  const void* Wk = d_in[3];
  const void* bk = d_in[4];
  const void* Wv = d_in[5];
  const void* bv = d_in[6];
  const void* Wo = d_in[7];
  const void* bo = d_in[8];

  int* flag = (int*)d_ws;
  ushort* base = (ushort*)((char*)d_ws + 256);

  // ws layout (33.56 MB budget):
  //   q:[0,ELX) k:[ELX,2ELX) vt:[2ELX,3ELX)
  //   w3 (3*ELW, dead after qkv) and o (ELX) share [3ELX,4ELX)
  // xb (bf16 copy of x, ELX ushorts) lives in d_out: dead before proj_pipe
  // writes it.
  ushort* q_ws  = base;
  ushort* k_ws  = q_ws + ELX;
  ushort* vt_ws = k_ws + ELX;
  ushort* w3    = vt_ws + ELX;
  ushort* o_ws  = vt_ws + ELX;
  ushort* xb    = (ushort*)d_out;

  convert4<<<dim3(3584), dim3(256), 0, stream>>>(Wq, Wk, Wv, x, w3, xb, flag);
  qkv_pipe<<<dim3(768), dim3(256), 0, stream>>>(xb, w3, bq, bk, bv,
                                                q_ws, k_ws, vt_ws, flag);
  attn3<<<dim3(1024), dim3(256), 0, stream>>>(q_ws, k_ws, vt_ws, o_ws);
  proj_pipe<<<dim3(256), dim3(512), 0, stream>>>(o_ws, Wo, bo, d_out, flag);
}